// Round 1
// baseline (9556.333 us; speedup 1.0000x reference)
//
#include <hip/hip_runtime.h>
#include <math.h>

#define S_ 48
#define B_ 64
#define D_ 300
#define HE_ 300
#define HD_ 256
#define E_ 50
#define A_ 128
#define T_ 50
#define N_ (S_*B_)   // 3072

__device__ __forceinline__ float sigm(float x){ return 1.0f/(1.0f + expf(-x)); }

// ---------------------------------------------------------------------------
// Generic GEMM: C(M,N) = A(M,K) @ W(N,K)^T + bias(N)
// MODE 0: store C row-major
// MODE 1: v = tanh(acc+bias); cols [0,256) -> C[m*256+n], [256,512) -> C2
// ---------------------------------------------------------------------------
template<int MODE>
__global__ __launch_bounds__(256)
void gemm_bias_kernel(const float* __restrict__ A, const float* __restrict__ W,
                      const float* __restrict__ bias, float* __restrict__ C,
                      float* __restrict__ C2, int M, int N, int K)
{
  __shared__ float As[16][64];
  __shared__ float Ws[16][64];
  const int tid = threadIdx.x;
  const int bm = blockIdx.y * 64;
  const int bn = blockIdx.x * 64;
  const int tx = tid & 15, ty = tid >> 4;
  const int lr = tid >> 2;
  const int lk = (tid & 3) << 2;
  float acc[4][4] = {{0.f}};
  for (int kb = 0; kb < K; kb += 16) {
    // A tile 64x16
    {
      const int row = bm + lr;
      const int k = kb + lk;
      const float* ap = A + (size_t)row * K + k;
      float4 v = make_float4(0.f,0.f,0.f,0.f);
      if (k + 3 < K) v = *reinterpret_cast<const float4*>(ap);
      else {
        if (k   < K) v.x = ap[0];
        if (k+1 < K) v.y = ap[1];
        if (k+2 < K) v.z = ap[2];
        if (k+3 < K) v.w = ap[3];
      }
      As[lk][lr]=v.x; As[lk+1][lr]=v.y; As[lk+2][lr]=v.z; As[lk+3][lr]=v.w;
    }
    // W tile 64x16
    {
      const int col = bn + lr;
      const int k = kb + lk;
      float4 v = make_float4(0.f,0.f,0.f,0.f);
      if (col < N) {
        const float* wp = W + (size_t)col * K + k;
        if (k + 3 < K) v = *reinterpret_cast<const float4*>(wp);
        else {
          if (k   < K) v.x = wp[0];
          if (k+1 < K) v.y = wp[1];
          if (k+2 < K) v.z = wp[2];
          if (k+3 < K) v.w = wp[3];
        }
      }
      Ws[lk][lr]=v.x; Ws[lk+1][lr]=v.y; Ws[lk+2][lr]=v.z; Ws[lk+3][lr]=v.w;
    }
    __syncthreads();
    #pragma unroll
    for (int kk = 0; kk < 16; ++kk) {
      float4 a4 = *reinterpret_cast<const float4*>(&As[kk][ty<<2]);
      float4 w4 = *reinterpret_cast<const float4*>(&Ws[kk][tx<<2]);
      const float* a = reinterpret_cast<const float*>(&a4);
      const float* w = reinterpret_cast<const float*>(&w4);
      #pragma unroll
      for (int i = 0; i < 4; ++i)
        #pragma unroll
        for (int j = 0; j < 4; ++j)
          acc[i][j] = fmaf(a[i], w[j], acc[i][j]);
    }
    __syncthreads();
  }
  #pragma unroll
  for (int i = 0; i < 4; ++i) {
    const int m = bm + (ty<<2) + i;
    #pragma unroll
    for (int j = 0; j < 4; ++j) {
      const int n = bn + (tx<<2) + j;
      if (n < N) {
        float v = acc[i][j] + bias[n];
        if (MODE == 0) {
          C[(size_t)m*N + n] = v;
        } else {
          v = tanhf(v);
          if (n < HD_) C[(size_t)m*HD_ + n] = v;
          else         C2[(size_t)m*HD_ + (n-HD_)] = v;
        }
      }
    }
  }
}

// ---------------------------------------------------------------------------
// shared tile MAC: 3 gates, BM=64 rows (micro 4) x BN=16 cols (micro 1), BK=32
// ---------------------------------------------------------------------------
__device__ __forceinline__ void tile_mac(const float (*As)[64], const float (*Ws)[16][36],
                                         int tcol, int trow,
                                         float* accr, float* accz, float* accn)
{
  #pragma unroll
  for (int kk = 0; kk < 32; kk += 4) {
    float4 wr4 = *reinterpret_cast<const float4*>(&Ws[0][tcol][kk]);
    float4 wz4 = *reinterpret_cast<const float4*>(&Ws[1][tcol][kk]);
    float4 wn4 = *reinterpret_cast<const float4*>(&Ws[2][tcol][kk]);
    const float* wr = reinterpret_cast<const float*>(&wr4);
    const float* wz = reinterpret_cast<const float*>(&wz4);
    const float* wn = reinterpret_cast<const float*>(&wn4);
    #pragma unroll
    for (int u = 0; u < 4; ++u) {
      float4 a4 = *reinterpret_cast<const float4*>(&As[kk+u][trow]);
      const float* a = reinterpret_cast<const float*>(&a4);
      #pragma unroll
      for (int q = 0; q < 4; ++q) {
        accr[q] = fmaf(a[q], wr[u], accr[q]);
        accz[q] = fmaf(a[q], wz[u], accz[q]);
        accn[q] = fmaf(a[q], wn[u], accn[q]);
      }
    }
  }
}

// ---------------------------------------------------------------------------
// Encoder recurrent step (both directions in one launch, blockIdx.z = dir)
// gi = x@Wih^T + bih precomputed (S,B,900). Computes h_new = GRU(gi[t], h).
// layer 0: writes x0[tt][b][dir*300 + j]; layer 1: enc[tt][b][j] += h_new
// ---------------------------------------------------------------------------
__global__ __launch_bounds__(256)
void enc_step_kernel(const float* __restrict__ gi_f, const float* __restrict__ gi_b,
                     const float* __restrict__ Whh_f, const float* __restrict__ Whh_b,
                     const float* __restrict__ bhh_f, const float* __restrict__ bhh_b,
                     const float* __restrict__ hin_f, float* __restrict__ hout_f,
                     const float* __restrict__ hin_b, float* __restrict__ hout_b,
                     float* __restrict__ out, int t, int layer)
{
  const int dir = blockIdx.z;
  const float* gi  = dir ? gi_b  : gi_f;
  const float* W   = dir ? Whh_b : Whh_f;
  const float* bhh = dir ? bhh_b : bhh_f;
  const float* hin = dir ? hin_b : hin_f;
  float* hout = dir ? hout_b : hout_f;
  const int tt = dir ? (S_-1 - t) : t;

  __shared__ float As[32][64];
  __shared__ float Ws[3][16][36];
  const int tid = threadIdx.x;
  const int bn = blockIdx.x * 16;
  const int tcol = tid & 15;
  const int trow = (tid >> 4) << 2;
  float accr[4]={0,0,0,0}, accz[4]={0,0,0,0}, accn[4]={0,0,0,0};

  for (int kb = 0; kb < HE_; kb += 32) {
    __syncthreads();
    // h tile 64x32 (vector loads)
    #pragma unroll
    for (int j = 0; j < 2; ++j) {
      int i = tid + j*256;
      int row = i >> 3;
      int k = (i & 7) << 2;
      const float* ap = hin + (size_t)row*HE_ + kb + k;
      float4 v = make_float4(0.f,0.f,0.f,0.f);
      if (kb + k + 3 < HE_) v = *reinterpret_cast<const float4*>(ap);
      else {
        if (kb+k   < HE_) v.x = ap[0];
        if (kb+k+1 < HE_) v.y = ap[1];
        if (kb+k+2 < HE_) v.z = ap[2];
        if (kb+k+3 < HE_) v.w = ap[3];
      }
      As[k  ][row] = v.x; As[k+1][row] = v.y; As[k+2][row] = v.z; As[k+3][row] = v.w;
    }
    // W tiles: 3 x 16 x 32
    #pragma unroll
    for (int j = 0; j < 6; ++j) {
      int i = tid + j*256;
      int g = i >> 9;
      int c = (i >> 5) & 15;
      int k = i & 31;
      float v = 0.0f;
      if (bn + c < HE_ && kb + k < HE_) v = W[(size_t)(g*HE_ + bn + c)*HE_ + kb + k];
      Ws[g][c][k] = v;
    }
    __syncthreads();
    tile_mac(As, Ws, tcol, trow, accr, accz, accn);
  }

  const int jcol = bn + tcol;
  if (jcol < HE_) {
    #pragma unroll
    for (int i = 0; i < 4; ++i) {
      const int row = trow + i;
      const size_t gbase = (size_t)(tt*B_ + row) * (3*HE_);
      float gr = gi[gbase + jcol];
      float gz = gi[gbase + HE_ + jcol];
      float gn = gi[gbase + 2*HE_ + jcol];
      float r = sigm(gr + accr[i] + bhh[jcol]);
      float z = sigm(gz + accz[i] + bhh[HE_ + jcol]);
      float n = tanhf(gn + r*(accn[i] + bhh[2*HE_ + jcol]));
      float ho = hin[(size_t)row*HE_ + jcol];
      float hn = (1.0f - z)*n + z*ho;
      hout[(size_t)row*HE_ + jcol] = hn;
      if (layer == 0) out[(size_t)(tt*B_ + row)*(2*HE_) + dir*HE_ + jcol] = hn;
      else            out[(size_t)(tt*B_ + row)*HE_ + jcol] += hn;
    }
  }
}

// ---------------------------------------------------------------------------
// Decoder GRU cell: gates = A1@W1^T (+gather emb[p]) + A2@W2^T; A2 is h_old.
// ---------------------------------------------------------------------------
__global__ __launch_bounds__(256)
void dec_cell_kernel(const float* __restrict__ A1, const int* __restrict__ pin,
                     const float* __restrict__ emb, int K1,
                     const float* __restrict__ W1,
                     const float* __restrict__ A2, int K2,
                     const float* __restrict__ W2,
                     const float* __restrict__ bih, const float* __restrict__ bhh,
                     float* __restrict__ hnew)
{
  __shared__ float As[32][64];
  __shared__ float Ws[3][16][36];
  __shared__ int ps[64];
  const int tid = threadIdx.x;
  const int bm = blockIdx.y * 64;
  const int bn = blockIdx.x * 16;
  const int tcol = tid & 15;
  const int trow = (tid >> 4) << 2;
  float accr[4]={0,0,0,0}, accz[4]={0,0,0,0}, accin[4]={0,0,0,0}, acchn[4]={0,0,0,0};
  if (pin != nullptr && tid < 64) ps[tid] = pin[bm + tid];

  // segment 1: input part -> accr, accz, accin
  for (int kb = 0; kb < K1; kb += 32) {
    __syncthreads();
    if (pin != nullptr) {
      #pragma unroll
      for (int j = 0; j < 8; ++j) {
        int i = tid + j*256;
        int row = i >> 5;
        int k = i & 31;
        float v = 0.0f;
        if (kb + k < K1) v = emb[(size_t)ps[row]*K1 + kb + k];
        As[k][row] = v;
      }
    } else {
      #pragma unroll
      for (int j = 0; j < 2; ++j) {
        int i = tid + j*256;
        int row = i >> 3;
        int k = (i & 7) << 2;
        const float* ap = A1 + (size_t)(bm + row)*K1 + kb + k;
        float4 v = make_float4(0.f,0.f,0.f,0.f);
        if (kb + k + 3 < K1) v = *reinterpret_cast<const float4*>(ap);
        else {
          if (kb+k   < K1) v.x = ap[0];
          if (kb+k+1 < K1) v.y = ap[1];
          if (kb+k+2 < K1) v.z = ap[2];
          if (kb+k+3 < K1) v.w = ap[3];
        }
        As[k  ][row] = v.x; As[k+1][row] = v.y; As[k+2][row] = v.z; As[k+3][row] = v.w;
      }
    }
    #pragma unroll
    for (int j = 0; j < 6; ++j) {
      int i = tid + j*256;
      int g = i >> 9;
      int c = (i >> 5) & 15;
      int k = i & 31;
      float v = 0.0f;
      if (kb + k < K1) v = W1[(size_t)(g*HD_ + bn + c)*K1 + kb + k];
      Ws[g][c][k] = v;
    }
    __syncthreads();
    tile_mac(As, Ws, tcol, trow, accr, accz, accin);
  }
  // segment 2: hidden part -> accr, accz, acchn
  for (int kb = 0; kb < K2; kb += 32) {
    __syncthreads();
    #pragma unroll
    for (int j = 0; j < 2; ++j) {
      int i = tid + j*256;
      int row = i >> 3;
      int k = (i & 7) << 2;
      const float* ap = A2 + (size_t)(bm + row)*K2 + kb + k;
      float4 v = make_float4(0.f,0.f,0.f,0.f);
      if (kb + k + 3 < K2) v = *reinterpret_cast<const float4*>(ap);
      else {
        if (kb+k   < K2) v.x = ap[0];
        if (kb+k+1 < K2) v.y = ap[1];
        if (kb+k+2 < K2) v.z = ap[2];
        if (kb+k+3 < K2) v.w = ap[3];
      }
      As[k  ][row] = v.x; As[k+1][row] = v.y; As[k+2][row] = v.z; As[k+3][row] = v.w;
    }
    #pragma unroll
    for (int j = 0; j < 6; ++j) {
      int i = tid + j*256;
      int g = i >> 9;
      int c = (i >> 5) & 15;
      int k = i & 31;
      float v = 0.0f;
      if (kb + k < K2) v = W2[(size_t)(g*HD_ + bn + c)*K2 + kb + k];
      Ws[g][c][k] = v;
    }
    __syncthreads();
    tile_mac(As, Ws, tcol, trow, accr, accz, acchn);
  }

  const int c = bn + tcol;
  #pragma unroll
  for (int i = 0; i < 4; ++i) {
    const int m = bm + trow + i;
    float r = sigm(accr[i] + bih[c] + bhh[c]);
    float z = sigm(accz[i] + bih[HD_+c] + bhh[HD_+c]);
    float n = tanhf(accin[i] + bih[2*HD_+c] + r*(acchn[i] + bhh[2*HD_+c]));
    float ho = A2[(size_t)m*HD_ + c];
    hnew[(size_t)m*HD_ + c] = (1.0f - z)*n + z*ho;
  }
}

// ---------------------------------------------------------------------------
// logits + log_softmax + argmax. Block = 4 waves, 2 rows/wave, grid = N/8.
// WT is Wout transposed (256,128).
// ---------------------------------------------------------------------------
__global__ __launch_bounds__(256)
void logits_kernel(const float* __restrict__ h1, const float* __restrict__ WT,
                   const float* __restrict__ bout, float* __restrict__ Y,
                   int* __restrict__ p)
{
  __shared__ float hs[8][256];
  const int tid = threadIdx.x;
  const int m0 = blockIdx.x * 8;
  #pragma unroll
  for (int j = 0; j < 2; ++j) {
    int i = tid + j*256;
    int row = i >> 6;
    int k = (i & 63) << 2;
    *reinterpret_cast<float4*>(&hs[row][k]) =
        *reinterpret_cast<const float4*>(&h1[(size_t)(m0+row)*HD_ + k]);
  }
  __syncthreads();
  const int w = tid >> 6;
  const int lane = tid & 63;
  const int r0 = w*2;
  float acc00=0.f, acc01=0.f, acc10=0.f, acc11=0.f;
  #pragma unroll 4
  for (int k = 0; k < HD_; k += 4) {
    float4 a04 = *reinterpret_cast<const float4*>(&hs[r0][k]);
    float4 a14 = *reinterpret_cast<const float4*>(&hs[r0+1][k]);
    const float* a0 = reinterpret_cast<const float*>(&a04);
    const float* a1 = reinterpret_cast<const float*>(&a14);
    #pragma unroll
    for (int u = 0; u < 4; ++u) {
      float w0 = WT[(size_t)(k+u)*A_ + lane];
      float w1 = WT[(size_t)(k+u)*A_ + 64 + lane];
      acc00 = fmaf(a0[u], w0, acc00);
      acc01 = fmaf(a0[u], w1, acc01);
      acc10 = fmaf(a1[u], w0, acc10);
      acc11 = fmaf(a1[u], w1, acc11);
    }
  }
  float va[2][2] = {{acc00, acc01},{acc10, acc11}};
  #pragma unroll
  for (int r = 0; r < 2; ++r) {
    const int m = m0 + r0 + r;
    float v0 = va[r][0] + bout[lane];
    float v1 = va[r][1] + bout[64+lane];
    float mx = fmaxf(v0, v1);
    #pragma unroll
    for (int off = 32; off >= 1; off >>= 1) mx = fmaxf(mx, __shfl_xor(mx, off));
    float sum = expf(v0 - mx) + expf(v1 - mx);
    #pragma unroll
    for (int off = 32; off >= 1; off >>= 1) sum += __shfl_xor(sum, off);
    float lz = mx + logf(sum);
    Y[(size_t)m*A_ + lane]      = v0 - lz;
    Y[(size_t)m*A_ + 64 + lane] = v1 - lz;
    float bv; int bi;
    if (v0 >= v1) { bv = v0; bi = lane; } else { bv = v1; bi = 64 + lane; }
    #pragma unroll
    for (int off = 32; off >= 1; off >>= 1) {
      float ov = __shfl_xor(bv, off);
      int   oi = __shfl_xor(bi, off);
      if (ov > bv || (ov == bv && oi < bi)) { bv = ov; bi = oi; }
    }
    if (lane == 0) p[m] = bi;
  }
}

// transpose Wout (128,256)->(256,128), init p = SOS
__global__ __launch_bounds__(256)
void prep_kernel(const float* __restrict__ Wout, float* __restrict__ WT, int* __restrict__ p)
{
  int idx = blockIdx.x * 256 + threadIdx.x;
  if (idx < A_*HD_) {
    int c = idx >> 8;
    int k = idx & 255;
    WT[(size_t)k*A_ + c] = Wout[idx];
  }
  int t2 = idx - A_*HD_;
  if (t2 >= 0 && t2 < N_) p[t2] = 1;  // SOS
}

// ---------------------------------------------------------------------------
extern "C" void kernel_launch(void* const* d_in, const int* in_sizes, int n_in,
                              void* d_out, int out_size, void* d_ws, size_t ws_size,
                              hipStream_t stream)
{
  (void)in_sizes; (void)n_in; (void)out_size; (void)ws_size;
  const float* wv      = (const float*)d_in[0];
  const float* e0f_Wih = (const float*)d_in[1];
  const float* e0f_Whh = (const float*)d_in[2];
  const float* e0f_bih = (const float*)d_in[3];
  const float* e0f_bhh = (const float*)d_in[4];
  const float* e0b_Wih = (const float*)d_in[5];
  const float* e0b_Whh = (const float*)d_in[6];
  const float* e0b_bih = (const float*)d_in[7];
  const float* e0b_bhh = (const float*)d_in[8];
  const float* e1f_Wih = (const float*)d_in[9];
  const float* e1f_Whh = (const float*)d_in[10];
  const float* e1f_bih = (const float*)d_in[11];
  const float* e1f_bhh = (const float*)d_in[12];
  const float* e1b_Wih = (const float*)d_in[13];
  const float* e1b_Whh = (const float*)d_in[14];
  const float* e1b_bih = (const float*)d_in[15];
  const float* e1b_bhh = (const float*)d_in[16];
  const float* d0_Wih  = (const float*)d_in[17];
  const float* d0_Whh  = (const float*)d_in[18];
  const float* d0_bih  = (const float*)d_in[19];
  const float* d0_bhh  = (const float*)d_in[20];
  const float* d1_Wih  = (const float*)d_in[21];
  const float* d1_Whh  = (const float*)d_in[22];
  const float* d1_bih  = (const float*)d_in[23];
  const float* d1_bhh  = (const float*)d_in[24];
  const float* emb     = (const float*)d_in[25];
  const float* Wout    = (const float*)d_in[26];
  const float* bout    = (const float*)d_in[27];
  const float* Wh0     = (const float*)d_in[28];
  const float* bh0     = (const float*)d_in[29];

  float* ws = (float*)d_ws;
  size_t off = 0;
  auto alloc = [&](size_t n){ float* q = ws + off; off += n; return q; };
  float* giA = alloc((size_t)N_*3*HE_);   // 2,764,800
  float* giB = alloc((size_t)N_*3*HE_);
  float* x0  = alloc((size_t)N_*2*HE_);
  float* enc = alloc((size_t)N_*HE_);
  float* hfA = alloc((size_t)B_*HE_);
  float* hfB = alloc((size_t)B_*HE_);
  float* hbA = alloc((size_t)B_*HE_);
  float* hbB = alloc((size_t)B_*HE_);
  float* WT  = alloc((size_t)HD_*A_);
  int*   p   = (int*)alloc(N_);
  // decoder h buffers alias gi region (dead after encoder loops)
  float* h0A = giA;
  float* h0B = giA + (size_t)N_*HD_;
  float* h1A = giA + (size_t)2*N_*HD_;   // 3*N*HD = 2,359,296 <= N*3*HE
  float* h1B = giB;

  const dim3 blk(256);

  // ---- encoder layer 0 ----
  gemm_bias_kernel<0><<<dim3(15,48), blk, 0, stream>>>(wv, e0f_Wih, e0f_bih, giA, nullptr, N_, 3*HE_, D_);
  gemm_bias_kernel<0><<<dim3(15,48), blk, 0, stream>>>(wv, e0b_Wih, e0b_bih, giB, nullptr, N_, 3*HE_, D_);
  hipMemsetAsync(hfA, 0, (size_t)B_*HE_*sizeof(float), stream);
  hipMemsetAsync(hbA, 0, (size_t)B_*HE_*sizeof(float), stream);
  {
    float* hfi = hfA; float* hfo = hfB; float* hbi = hbA; float* hbo = hbB;
    for (int t = 0; t < S_; ++t) {
      enc_step_kernel<<<dim3(19,1,2), blk, 0, stream>>>(giA, giB, e0f_Whh, e0b_Whh,
          e0f_bhh, e0b_bhh, hfi, hfo, hbi, hbo, x0, t, 0);
      float* tmp = hfi; hfi = hfo; hfo = tmp;
      tmp = hbi; hbi = hbo; hbo = tmp;
    }
  }
  // ---- encoder layer 1 ----
  gemm_bias_kernel<0><<<dim3(15,48), blk, 0, stream>>>(x0, e1f_Wih, e1f_bih, giA, nullptr, N_, 3*HE_, 2*HE_);
  gemm_bias_kernel<0><<<dim3(15,48), blk, 0, stream>>>(x0, e1b_Wih, e1b_bih, giB, nullptr, N_, 3*HE_, 2*HE_);
  hipMemsetAsync(hfA, 0, (size_t)B_*HE_*sizeof(float), stream);
  hipMemsetAsync(hbA, 0, (size_t)B_*HE_*sizeof(float), stream);
  hipMemsetAsync(enc, 0, (size_t)N_*HE_*sizeof(float), stream);
  {
    float* hfi = hfA; float* hfo = hfB; float* hbi = hbA; float* hbo = hbB;
    for (int t = 0; t < S_; ++t) {
      enc_step_kernel<<<dim3(19,1,2), blk, 0, stream>>>(giA, giB, e1f_Whh, e1b_Whh,
          e1f_bhh, e1b_bhh, hfi, hfo, hbi, hbo, enc, t, 1);
      float* tmp = hfi; hfi = hfo; hfo = tmp;
      tmp = hbi; hbi = hbo; hbo = tmp;
    }
  }
  // ---- decoder init: h = tanh(enc@Wh0^T + bh0) split into h0, h1 ----
  gemm_bias_kernel<1><<<dim3(8,48), blk, 0, stream>>>(enc, Wh0, bh0, h0A, h1A, N_, 2*HD_, HE_);
  prep_kernel<<<dim3(140), blk, 0, stream>>>(Wout, WT, p);

  // ---- decoder loop: 49 output steps ----
  {
    float* h0a = h0A; float* h0b = h0B; float* h1a = h1A; float* h1b = h1B;
    float* Yo = (float*)d_out;
    for (int s = 0; s < T_-1; ++s) {
      dec_cell_kernel<<<dim3(16,48), blk, 0, stream>>>(nullptr, p, emb, E_, d0_Wih,
          h0a, HD_, d0_Whh, d0_bih, d0_bhh, h0b);
      dec_cell_kernel<<<dim3(16,48), blk, 0, stream>>>(h0b, nullptr, nullptr, HD_, d1_Wih,
          h1a, HD_, d1_Whh, d1_bih, d1_bhh, h1b);
      logits_kernel<<<dim3(N_/8), blk, 0, stream>>>(h1b, WT, bout,
          Yo + (size_t)s*N_*A_, p);
      float* tmp = h0a; h0a = h0b; h0b = tmp;
      tmp = h1a; h1a = h1b; h1b = tmp;
    }
  }
}

// Round 3
// 6855.830 us; speedup vs baseline: 1.3939x; 1.3939x over previous
//
#include <hip/hip_runtime.h>
#include <math.h>

#define S_ 48
#define B_ 64
#define D_ 300
#define HE_ 300
#define HD_ 256
#define E_ 50
#define A_ 128
#define T_ 50
#define N_ (S_*B_)   // 3072
#define NR 6         // rows per thread-half in decoder

__device__ __forceinline__ float sigm(float x){ return 1.0f/(1.0f + expf(-x)); }

// ---------------------------------------------------------------------------
// Generic GEMM: C(M,N) = A(M,K) @ W(N,K)^T + bias(N)   (round-1 proven)
// MODE 0: store C row-major
// MODE 1: v = tanh(acc+bias); cols [0,256) -> C[m*256+n], [256,512) -> C2
// ---------------------------------------------------------------------------
template<int MODE>
__global__ __launch_bounds__(256)
void gemm_bias_kernel(const float* __restrict__ A, const float* __restrict__ W,
                      const float* __restrict__ bias, float* __restrict__ C,
                      float* __restrict__ C2, int M, int N, int K)
{
  __shared__ float As[16][64];
  __shared__ float Ws[16][64];
  const int tid = threadIdx.x;
  const int bm = blockIdx.y * 64;
  const int bn = blockIdx.x * 64;
  const int tx = tid & 15, ty = tid >> 4;
  const int lr = tid >> 2;
  const int lk = (tid & 3) << 2;
  float acc[4][4] = {{0.f}};
  for (int kb = 0; kb < K; kb += 16) {
    {
      const int row = bm + lr;
      const int k = kb + lk;
      const float* ap = A + (size_t)row * K + k;
      float4 v = make_float4(0.f,0.f,0.f,0.f);
      if (k + 3 < K) v = *reinterpret_cast<const float4*>(ap);
      else {
        if (k   < K) v.x = ap[0];
        if (k+1 < K) v.y = ap[1];
        if (k+2 < K) v.z = ap[2];
        if (k+3 < K) v.w = ap[3];
      }
      As[lk][lr]=v.x; As[lk+1][lr]=v.y; As[lk+2][lr]=v.z; As[lk+3][lr]=v.w;
    }
    {
      const int col = bn + lr;
      const int k = kb + lk;
      float4 v = make_float4(0.f,0.f,0.f,0.f);
      if (col < N) {
        const float* wp = W + (size_t)col * K + k;
        if (k + 3 < K) v = *reinterpret_cast<const float4*>(wp);
        else {
          if (k   < K) v.x = wp[0];
          if (k+1 < K) v.y = wp[1];
          if (k+2 < K) v.z = wp[2];
          if (k+3 < K) v.w = wp[3];
        }
      }
      Ws[lk][lr]=v.x; Ws[lk+1][lr]=v.y; Ws[lk+2][lr]=v.z; Ws[lk+3][lr]=v.w;
    }
    __syncthreads();
    #pragma unroll
    for (int kk = 0; kk < 16; ++kk) {
      float4 a4 = *reinterpret_cast<const float4*>(&As[kk][ty<<2]);
      float4 w4 = *reinterpret_cast<const float4*>(&Ws[kk][tx<<2]);
      const float* a = reinterpret_cast<const float*>(&a4);
      const float* w = reinterpret_cast<const float*>(&w4);
      #pragma unroll
      for (int i = 0; i < 4; ++i)
        #pragma unroll
        for (int j = 0; j < 4; ++j)
          acc[i][j] = fmaf(a[i], w[j], acc[i][j]);
    }
    __syncthreads();
  }
  #pragma unroll
  for (int i = 0; i < 4; ++i) {
    const int m = bm + (ty<<2) + i;
    #pragma unroll
    for (int j = 0; j < 4; ++j) {
      const int n = bn + (tx<<2) + j;
      if (n < N) {
        float v = acc[i][j] + bias[n];
        if (MODE == 0) {
          C[(size_t)m*N + n] = v;
        } else {
          v = tanhf(v);
          if (n < HD_) C[(size_t)m*HD_ + n] = v;
          else         C2[(size_t)m*HD_ + (n-HD_)] = v;
        }
      }
    }
  }
}

// ---------------------------------------------------------------------------
// Encoder step tile MAC (round-1 proven)
// ---------------------------------------------------------------------------
__device__ __forceinline__ void tile_mac(const float (*As)[64], const float (*Ws)[16][36],
                                         int tcol, int trow,
                                         float* accr, float* accz, float* accn)
{
  #pragma unroll
  for (int kk = 0; kk < 32; kk += 4) {
    float4 wr4 = *reinterpret_cast<const float4*>(&Ws[0][tcol][kk]);
    float4 wz4 = *reinterpret_cast<const float4*>(&Ws[1][tcol][kk]);
    float4 wn4 = *reinterpret_cast<const float4*>(&Ws[2][tcol][kk]);
    const float* wr = reinterpret_cast<const float*>(&wr4);
    const float* wz = reinterpret_cast<const float*>(&wz4);
    const float* wn = reinterpret_cast<const float*>(&wn4);
    #pragma unroll
    for (int u = 0; u < 4; ++u) {
      float4 a4 = *reinterpret_cast<const float4*>(&As[kk+u][trow]);
      const float* a = reinterpret_cast<const float*>(&a4);
      #pragma unroll
      for (int q = 0; q < 4; ++q) {
        accr[q] = fmaf(a[q], wr[u], accr[q]);
        accz[q] = fmaf(a[q], wz[u], accz[q]);
        accn[q] = fmaf(a[q], wn[u], accn[q]);
      }
    }
  }
}

// ---------------------------------------------------------------------------
// Encoder recurrent step (round-1 proven, verbatim)
// ---------------------------------------------------------------------------
__global__ __launch_bounds__(256)
void enc_step_kernel(const float* __restrict__ gi_f, const float* __restrict__ gi_b,
                     const float* __restrict__ Whh_f, const float* __restrict__ Whh_b,
                     const float* __restrict__ bhh_f, const float* __restrict__ bhh_b,
                     const float* __restrict__ hin_f, float* __restrict__ hout_f,
                     const float* __restrict__ hin_b, float* __restrict__ hout_b,
                     float* __restrict__ out, int t, int layer)
{
  const int dir = blockIdx.z;
  const float* gi  = dir ? gi_b  : gi_f;
  const float* W   = dir ? Whh_b : Whh_f;
  const float* bhh = dir ? bhh_b : bhh_f;
  const float* hin = dir ? hin_b : hin_f;
  float* hout = dir ? hout_b : hout_f;
  const int tt = dir ? (S_-1 - t) : t;

  __shared__ float As[32][64];
  __shared__ float Ws[3][16][36];
  const int tid = threadIdx.x;
  const int bn = blockIdx.x * 16;
  const int tcol = tid & 15;
  const int trow = (tid >> 4) << 2;
  float accr[4]={0,0,0,0}, accz[4]={0,0,0,0}, accn[4]={0,0,0,0};

  for (int kb = 0; kb < HE_; kb += 32) {
    __syncthreads();
    #pragma unroll
    for (int j = 0; j < 2; ++j) {
      int i = tid + j*256;
      int row = i >> 3;
      int k = (i & 7) << 2;
      const float* ap = hin + (size_t)row*HE_ + kb + k;
      float4 v = make_float4(0.f,0.f,0.f,0.f);
      if (kb + k + 3 < HE_) v = *reinterpret_cast<const float4*>(ap);
      else {
        if (kb+k   < HE_) v.x = ap[0];
        if (kb+k+1 < HE_) v.y = ap[1];
        if (kb+k+2 < HE_) v.z = ap[2];
        if (kb+k+3 < HE_) v.w = ap[3];
      }
      As[k  ][row] = v.x; As[k+1][row] = v.y; As[k+2][row] = v.z; As[k+3][row] = v.w;
    }
    #pragma unroll
    for (int j = 0; j < 6; ++j) {
      int i = tid + j*256;
      int g = i >> 9;
      int c = (i >> 5) & 15;
      int k = i & 31;
      float v = 0.0f;
      if (bn + c < HE_ && kb + k < HE_) v = W[(size_t)(g*HE_ + bn + c)*HE_ + kb + k];
      Ws[g][c][k] = v;
    }
    __syncthreads();
    tile_mac(As, Ws, tcol, trow, accr, accz, accn);
  }

  const int jcol = bn + tcol;
  if (jcol < HE_) {
    #pragma unroll
    for (int i = 0; i < 4; ++i) {
      const int row = trow + i;
      const size_t gbase = (size_t)(tt*B_ + row) * (3*HE_);
      float gr = gi[gbase + jcol];
      float gz = gi[gbase + HE_ + jcol];
      float gn = gi[gbase + 2*HE_ + jcol];
      float r = sigm(gr + accr[i] + bhh[jcol]);
      float z = sigm(gz + accz[i] + bhh[HE_ + jcol]);
      float n = tanhf(gn + r*(accn[i] + bhh[2*HE_ + jcol]));
      float ho = hin[(size_t)row*HE_ + jcol];
      float hn = (1.0f - z)*n + z*ho;
      hout[(size_t)row*HE_ + jcol] = hn;
      if (layer == 0) out[(size_t)(tt*B_ + row)*(2*HE_) + dir*HE_ + jcol] = hn;
      else            out[(size_t)(tt*B_ + row)*HE_ + jcol] += hn;
    }
  }
}

// ---------------------------------------------------------------------------
// Weight transpose: in (NC, NK) row-major -> out (NK, NC)
// ---------------------------------------------------------------------------
__global__ __launch_bounds__(256)
void transpose_kernel(const float* __restrict__ in, float* __restrict__ out,
                      int NC, int NK)
{
  int idx = blockIdx.x * 256 + threadIdx.x;
  if (idx < NC*NK) {
    int cI = idx / NK, kI = idx % NK;
    out[(size_t)kI*NC + cI] = in[idx];
  }
}

// ---------------------------------------------------------------------------
// Persistent decoder, ZERO cross-block dependencies.
// 256 blocks x 512 threads. Block bb owns rows [bb*12, bb*12+12).
// h0/h1/e state in LDS; weights streamed k-major from L2.
// Thread t: c = t&255 (gate-column), half = t>>8 (rows half*6 .. +6).
// ---------------------------------------------------------------------------
__global__ __launch_bounds__(512, 2)
void dec_persistent(const float* __restrict__ WihT0,  // [50][768]
                    const float* __restrict__ WhhT0,  // [256][768]
                    const float* __restrict__ WihT1,  // [256][768]
                    const float* __restrict__ WhhT1,  // [256][768]
                    const float* __restrict__ WoutT,  // [256][128]
                    const float* __restrict__ bih0, const float* __restrict__ bhh0,
                    const float* __restrict__ bih1, const float* __restrict__ bhh1,
                    const float* __restrict__ bout,
                    const float* __restrict__ emb,    // [128][50]
                    const float* __restrict__ h0init, const float* __restrict__ h1init,
                    float* __restrict__ Y)
{
  __shared__ float h0s[12][256];
  __shared__ float h1s[12][256];
  __shared__ float es[12][52];
  const int tid = threadIdx.x;
  const int bb = blockIdx.x;
  const int R0 = bb * 12;
  const int c  = tid & 255;
  const int half = tid >> 8;
  const int r0 = half * NR;

  // init state
  for (int i = tid; i < 12*64; i += 512) {
    int r = i >> 6;
    int k = (i & 63) << 2;
    *reinterpret_cast<float4*>(&h0s[r][k]) =
        *reinterpret_cast<const float4*>(&h0init[(size_t)(R0+r)*HD_ + k]);
    *reinterpret_cast<float4*>(&h1s[r][k]) =
        *reinterpret_cast<const float4*>(&h1init[(size_t)(R0+r)*HD_ + k]);
  }
  for (int i = tid; i < 12*E_; i += 512) {
    int r = i / E_, k = i % E_;
    es[r][k] = emb[E_ + k];   // emb[SOS=1]
  }
  // preload biases (constant across steps)
  const float b0r = bih0[c] + bhh0[c];
  const float b0z = bih0[HD_+c] + bhh0[HD_+c];
  const float b0ni = bih0[2*HD_+c];
  const float b0nh = bhh0[2*HD_+c];
  const float b1r = bih1[c] + bhh1[c];
  const float b1z = bih1[HD_+c] + bhh1[HD_+c];
  const float b1ni = bih1[2*HD_+c];
  const float b1nh = bhh1[2*HD_+c];
  const float bo0 = bout[tid & 63];
  const float bo1 = bout[64 + (tid & 63)];
  __syncthreads();

  for (int s = 0; s < T_-1; ++s) {
    // ================= cell 0: x = es (K=50), h = h0s (K=256) =============
    float ar[NR], az[NR], ani[NR], anh[NR];
    #pragma unroll
    for (int r = 0; r < NR; ++r) { ar[r]=0.f; az[r]=0.f; ani[r]=0.f; anh[r]=0.f; }
    for (int k = 0; k < E_; k += 2) {
      const float* wk = WihT0 + (size_t)k*768;
      float wr0=wk[c],     wz0=wk[HD_+c],     wn0=wk[2*HD_+c];
      float wr1=wk[768+c], wz1=wk[768+HD_+c], wn1=wk[768+2*HD_+c];
      #pragma unroll
      for (int r = 0; r < NR; ++r) {
        float2 x = *reinterpret_cast<const float2*>(&es[r0+r][k]);
        ar[r]=fmaf(x.x,wr0,ar[r]);  ar[r]=fmaf(x.y,wr1,ar[r]);
        az[r]=fmaf(x.x,wz0,az[r]);  az[r]=fmaf(x.y,wz1,az[r]);
        ani[r]=fmaf(x.x,wn0,ani[r]); ani[r]=fmaf(x.y,wn1,ani[r]);
      }
    }
    for (int k = 0; k < HD_; k += 4) {
      float wr[4], wz[4], wn[4];
      #pragma unroll
      for (int u = 0; u < 4; ++u) {
        const float* wk = WhhT0 + (size_t)(k+u)*768;
        wr[u]=wk[c]; wz[u]=wk[HD_+c]; wn[u]=wk[2*HD_+c];
      }
      #pragma unroll
      for (int r = 0; r < NR; ++r) {
        float4 x = *reinterpret_cast<const float4*>(&h0s[r0+r][k]);
        ar[r]=fmaf(x.x,wr[0],ar[r]); ar[r]=fmaf(x.y,wr[1],ar[r]);
        ar[r]=fmaf(x.z,wr[2],ar[r]); ar[r]=fmaf(x.w,wr[3],ar[r]);
        az[r]=fmaf(x.x,wz[0],az[r]); az[r]=fmaf(x.y,wz[1],az[r]);
        az[r]=fmaf(x.z,wz[2],az[r]); az[r]=fmaf(x.w,wz[3],az[r]);
        anh[r]=fmaf(x.x,wn[0],anh[r]); anh[r]=fmaf(x.y,wn[1],anh[r]);
        anh[r]=fmaf(x.z,wn[2],anh[r]); anh[r]=fmaf(x.w,wn[3],anh[r]);
      }
    }
    __syncthreads();   // all reads of h0s/es complete
    {
      float hnew[NR];
      #pragma unroll
      for (int r = 0; r < NR; ++r) {
        float rg = sigm(ar[r] + b0r);
        float zg = sigm(az[r] + b0z);
        float ng = tanhf(ani[r] + b0ni + rg*(anh[r] + b0nh));
        float hold = h0s[r0+r][c];
        hnew[r] = (1.0f - zg)*ng + zg*hold;
      }
      #pragma unroll
      for (int r = 0; r < NR; ++r) h0s[r0+r][c] = hnew[r];
    }
    __syncthreads();
    // ================= cell 1: x = h0s (K=256), h = h1s (K=256) ===========
    #pragma unroll
    for (int r = 0; r < NR; ++r) { ar[r]=0.f; az[r]=0.f; ani[r]=0.f; anh[r]=0.f; }
    for (int k = 0; k < HD_; k += 4) {
      float wr[4], wz[4], wn[4];
      #pragma unroll
      for (int u = 0; u < 4; ++u) {
        const float* wk = WihT1 + (size_t)(k+u)*768;
        wr[u]=wk[c]; wz[u]=wk[HD_+c]; wn[u]=wk[2*HD_+c];
      }
      #pragma unroll
      for (int r = 0; r < NR; ++r) {
        float4 x = *reinterpret_cast<const float4*>(&h0s[r0+r][k]);
        ar[r]=fmaf(x.x,wr[0],ar[r]); ar[r]=fmaf(x.y,wr[1],ar[r]);
        ar[r]=fmaf(x.z,wr[2],ar[r]); ar[r]=fmaf(x.w,wr[3],ar[r]);
        az[r]=fmaf(x.x,wz[0],az[r]); az[r]=fmaf(x.y,wz[1],az[r]);
        az[r]=fmaf(x.z,wz[2],az[r]); az[r]=fmaf(x.w,wz[3],az[r]);
        ani[r]=fmaf(x.x,wn[0],ani[r]); ani[r]=fmaf(x.y,wn[1],ani[r]);
        ani[r]=fmaf(x.z,wn[2],ani[r]); ani[r]=fmaf(x.w,wn[3],ani[r]);
      }
    }
    for (int k = 0; k < HD_; k += 4) {
      float wr[4], wz[4], wn[4];
      #pragma unroll
      for (int u = 0; u < 4; ++u) {
        const float* wk = WhhT1 + (size_t)(k+u)*768;
        wr[u]=wk[c]; wz[u]=wk[HD_+c]; wn[u]=wk[2*HD_+c];
      }
      #pragma unroll
      for (int r = 0; r < NR; ++r) {
        float4 x = *reinterpret_cast<const float4*>(&h1s[r0+r][k]);
        ar[r]=fmaf(x.x,wr[0],ar[r]); ar[r]=fmaf(x.y,wr[1],ar[r]);
        ar[r]=fmaf(x.z,wr[2],ar[r]); ar[r]=fmaf(x.w,wr[3],ar[r]);
        az[r]=fmaf(x.x,wz[0],az[r]); az[r]=fmaf(x.y,wz[1],az[r]);
        az[r]=fmaf(x.z,wz[2],az[r]); az[r]=fmaf(x.w,wz[3],az[r]);
        anh[r]=fmaf(x.x,wn[0],anh[r]); anh[r]=fmaf(x.y,wn[1],anh[r]);
        anh[r]=fmaf(x.z,wn[2],anh[r]); anh[r]=fmaf(x.w,wn[3],anh[r]);
      }
    }
    __syncthreads();
    {
      float hnew[NR];
      #pragma unroll
      for (int r = 0; r < NR; ++r) {
        float rg = sigm(ar[r] + b1r);
        float zg = sigm(az[r] + b1z);
        float ng = tanhf(ani[r] + b1ni + rg*(anh[r] + b1nh));
        float hold = h1s[r0+r][c];
        hnew[r] = (1.0f - zg)*ng + zg*hold;
      }
      #pragma unroll
      for (int r = 0; r < NR; ++r) h1s[r0+r][c] = hnew[r];
    }
    __syncthreads();
    // ================= logits + log_softmax + argmax + emb feedback =======
    {
      const int w = tid >> 6;
      const int lane = tid & 63;
      if (w < 6) {
        const int row0 = 2*w;
        float a00=0.f, a01=0.f, a10=0.f, a11=0.f;
        for (int k = 0; k < HD_; k += 2) {
          float w00 = WoutT[(size_t)k*A_ + lane];
          float w01 = WoutT[(size_t)k*A_ + 64 + lane];
          float w10 = WoutT[(size_t)(k+1)*A_ + lane];
          float w11 = WoutT[(size_t)(k+1)*A_ + 64 + lane];
          float2 hv0 = *reinterpret_cast<const float2*>(&h1s[row0][k]);
          float2 hv1 = *reinterpret_cast<const float2*>(&h1s[row0+1][k]);
          a00 = fmaf(hv0.x, w00, a00); a00 = fmaf(hv0.y, w10, a00);
          a01 = fmaf(hv0.x, w01, a01); a01 = fmaf(hv0.y, w11, a01);
          a10 = fmaf(hv1.x, w00, a10); a10 = fmaf(hv1.y, w10, a10);
          a11 = fmaf(hv1.x, w01, a11); a11 = fmaf(hv1.y, w11, a11);
        }
        float va[2][2] = {{a00,a01},{a10,a11}};
        #pragma unroll
        for (int rr = 0; rr < 2; ++rr) {
          const int row = row0 + rr;
          float v0 = va[rr][0] + bo0;
          float v1 = va[rr][1] + bo1;
          float mx = fmaxf(v0, v1);
          #pragma unroll
          for (int off = 32; off >= 1; off >>= 1) mx = fmaxf(mx, __shfl_xor(mx, off));
          float sum = expf(v0 - mx) + expf(v1 - mx);
          #pragma unroll
          for (int off = 32; off >= 1; off >>= 1) sum += __shfl_xor(sum, off);
          float lz = mx + logf(sum);
          float* Yr = Y + ((size_t)s*N_ + R0 + row)*A_;
          Yr[lane]      = v0 - lz;
          Yr[64 + lane] = v1 - lz;
          float bv; int bi;
          if (v0 >= v1) { bv = v0; bi = lane; } else { bv = v1; bi = 64 + lane; }
          #pragma unroll
          for (int off = 32; off >= 1; off >>= 1) {
            float ov = __shfl_xor(bv, off);
            int   oi = __shfl_xor(bi, off);
            if (ov > bv || (ov == bv && oi < bi)) { bv = ov; bi = oi; }
          }
          if (lane < E_) es[row][lane] = emb[(size_t)bi*E_ + lane];
        }
      }
    }
    __syncthreads();   // es (and h state) ready for next step
  }
}

// ---------------------------------------------------------------------------
extern "C" void kernel_launch(void* const* d_in, const int* in_sizes, int n_in,
                              void* d_out, int out_size, void* d_ws, size_t ws_size,
                              hipStream_t stream)
{
  (void)in_sizes; (void)n_in; (void)out_size; (void)ws_size;
  const float* wv      = (const float*)d_in[0];
  const float* e0f_Wih = (const float*)d_in[1];
  const float* e0f_Whh = (const float*)d_in[2];
  const float* e0f_bih = (const float*)d_in[3];
  const float* e0f_bhh = (const float*)d_in[4];
  const float* e0b_Wih = (const float*)d_in[5];
  const float* e0b_Whh = (const float*)d_in[6];
  const float* e0b_bih = (const float*)d_in[7];
  const float* e0b_bhh = (const float*)d_in[8];
  const float* e1f_Wih = (const float*)d_in[9];
  const float* e1f_Whh = (const float*)d_in[10];
  const float* e1f_bih = (const float*)d_in[11];
  const float* e1f_bhh = (const float*)d_in[12];
  const float* e1b_Wih = (const float*)d_in[13];
  const float* e1b_Whh = (const float*)d_in[14];
  const float* e1b_bih = (const float*)d_in[15];
  const float* e1b_bhh = (const float*)d_in[16];
  const float* d0_Wih  = (const float*)d_in[17];
  const float* d0_Whh  = (const float*)d_in[18];
  const float* d0_bih  = (const float*)d_in[19];
  const float* d0_bhh  = (const float*)d_in[20];
  const float* d1_Wih  = (const float*)d_in[21];
  const float* d1_Whh  = (const float*)d_in[22];
  const float* d1_bih  = (const float*)d_in[23];
  const float* d1_bhh  = (const float*)d_in[24];
  const float* emb     = (const float*)d_in[25];
  const float* Wout    = (const float*)d_in[26];
  const float* bout    = (const float*)d_in[27];
  const float* Wh0     = (const float*)d_in[28];
  const float* bh0     = (const float*)d_in[29];

  float* ws = (float*)d_ws;
  size_t off = 0;
  auto alloc = [&](size_t n){ float* q = ws + off; off += n; return q; };
  float* giA = alloc((size_t)N_*3*HE_);   // 2,764,800
  float* giB = alloc((size_t)N_*3*HE_);
  float* x0  = alloc((size_t)N_*2*HE_);   // 1,843,200 (reused for WT after layer-1 gemms)
  float* enc = alloc((size_t)N_*HE_);
  float* hfA = alloc((size_t)B_*HE_);
  float* hfB = alloc((size_t)B_*HE_);
  float* hbA = alloc((size_t)B_*HE_);
  float* hbB = alloc((size_t)B_*HE_);
  // decoder h-init buffers alias giA (dead after encoder)
  float* h0A = giA;
  float* h1A = giA + (size_t)N_*HD_;
  // transposed decoder weights alias x0 (dead after layer-1 gemms): 660,992 floats
  float* WihT0 = x0;                      // 50 x 768
  float* WhhT0 = WihT0 + (size_t)E_*768;  // 256 x 768
  float* WihT1 = WhhT0 + (size_t)HD_*768;
  float* WhhT1 = WihT1 + (size_t)HD_*768;
  float* WoutT = WhhT1 + (size_t)HD_*768; // 256 x 128
  float* Y = (float*)d_out;

  const dim3 blk(256);

  // ---- encoder layer 0 ----
  gemm_bias_kernel<0><<<dim3(15,48), blk, 0, stream>>>(wv, e0f_Wih, e0f_bih, giA, nullptr, N_, 3*HE_, D_);
  gemm_bias_kernel<0><<<dim3(15,48), blk, 0, stream>>>(wv, e0b_Wih, e0b_bih, giB, nullptr, N_, 3*HE_, D_);
  hipMemsetAsync(hfA, 0, (size_t)B_*HE_*sizeof(float), stream);
  hipMemsetAsync(hbA, 0, (size_t)B_*HE_*sizeof(float), stream);
  {
    float* hfi = hfA; float* hfo = hfB; float* hbi = hbA; float* hbo = hbB;
    for (int t = 0; t < S_; ++t) {
      enc_step_kernel<<<dim3(19,1,2), blk, 0, stream>>>(giA, giB, e0f_Whh, e0b_Whh,
          e0f_bhh, e0b_bhh, hfi, hfo, hbi, hbo, x0, t, 0);
      float* tmp = hfi; hfi = hfo; hfo = tmp;
      tmp = hbi; hbi = hbo; hbo = tmp;
    }
  }
  // ---- encoder layer 1 ----
  gemm_bias_kernel<0><<<dim3(15,48), blk, 0, stream>>>(x0, e1f_Wih, e1f_bih, giA, nullptr, N_, 3*HE_, 2*HE_);
  gemm_bias_kernel<0><<<dim3(15,48), blk, 0, stream>>>(x0, e1b_Wih, e1b_bih, giB, nullptr, N_, 3*HE_, 2*HE_);
  hipMemsetAsync(hfA, 0, (size_t)B_*HE_*sizeof(float), stream);
  hipMemsetAsync(hbA, 0, (size_t)B_*HE_*sizeof(float), stream);
  hipMemsetAsync(enc, 0, (size_t)N_*HE_*sizeof(float), stream);
  {
    float* hfi = hfA; float* hfo = hfB; float* hbi = hbA; float* hbo = hbB;
    for (int t = 0; t < S_; ++t) {
      enc_step_kernel<<<dim3(19,1,2), blk, 0, stream>>>(giA, giB, e1f_Whh, e1b_Whh,
          e1f_bhh, e1b_bhh, hfi, hfo, hbi, hbo, enc, t, 1);
      float* tmp = hfi; hfi = hfo; hfo = tmp;
      tmp = hbi; hbi = hbo; hbo = tmp;
    }
  }
  // ---- decoder init: h = tanh(enc@Wh0^T + bh0) -> h0A, h1A (in giA) ----
  gemm_bias_kernel<1><<<dim3(8,48), blk, 0, stream>>>(enc, Wh0, bh0, h0A, h1A, N_, 2*HD_, HE_);
  // ---- transpose decoder weights (x0 region now dead) ----
  transpose_kernel<<<dim3(150), blk, 0, stream>>>(d0_Wih, WihT0, 3*HD_, E_);
  transpose_kernel<<<dim3(768), blk, 0, stream>>>(d0_Whh, WhhT0, 3*HD_, HD_);
  transpose_kernel<<<dim3(768), blk, 0, stream>>>(d1_Wih, WihT1, 3*HD_, HD_);
  transpose_kernel<<<dim3(768), blk, 0, stream>>>(d1_Whh, WhhT1, 3*HD_, HD_);
  transpose_kernel<<<dim3(128), blk, 0, stream>>>(Wout,   WoutT, A_,    HD_);
  // ---- persistent decoder: one launch, zero cross-block sync ----
  dec_persistent<<<dim3(N_/12), dim3(512), 0, stream>>>(
      WihT0, WhhT0, WihT1, WhhT1, WoutT,
      d0_bih, d0_bhh, d1_bih, d1_bhh, bout,
      emb, h0A, h1A, Y);
}